// Round 1
// baseline (315.155 us; speedup 1.0000x reference)
//
#include <hip/hip_runtime.h>
#include <hip/hip_cooperative_groups.h>

namespace cg = cooperative_groups;

#define T_TOKENS 8192
#define MAX_NODES 8192
#define FEAT 256
#define NCHUNKS 1024
#define CHUNK 8                  // T_TOKENS / NCHUNKS
#define NSUPER 32
#define SUPER 32                 // chunks per supergroup
#define LIST_CAP 4096            // events/chunk cap (expected ~18, huge margin)
#define EV_STRIDE LIST_CAP

// entry = (node << 4) | (local_row << 1) | sign, local_row in [0,8)
#define APPLY_EVENT(eV, vV)                          \
    {                                                \
        const float sv_ = ((eV) & 1) ? -(vV) : (vV); \
        const int lr_ = ((eV) >> 1) & 7;             \
        d0 += (lr_ == 0) ? sv_ : 0.f;                \
        d1 += (lr_ == 1) ? sv_ : 0.f;                \
        d2 += (lr_ == 2) ? sv_ : 0.f;                \
        d3 += (lr_ == 3) ? sv_ : 0.f;                \
        d4 += (lr_ == 4) ? sv_ : 0.f;                \
        d5 += (lr_ == 5) ? sv_ : 0.f;                \
        d6 += (lr_ == 6) ? sv_ : 0.f;                \
        d7 += (lr_ == 7) ? sv_ : 0.f;                \
    }

// ---------------------------------------------------------------------------
// Fused cooperative kernel: one dispatch replaces memset + classify + scan.
// Phase 1 : block c classifies all nodes for its chunk, gathers the ~18
//           signed emb rows ONCE into registers d0..d7 (colsum = sum(d)).
//           Writes colsum[c] only (no evbuf, no atomics).
// sync    : grid-wide.
// Phase 2a: blocks 0..31 reduce colsum -> supersum (replaces memset+atomics).
// sync    : grid-wide.
// Phase 2b: 2-level exclusive prefix (<=31 supersum + <=31 colsum rows,
//           8 loads in flight), then out rows = run + running sum of d.
// ---------------------------------------------------------------------------
__global__ __launch_bounds__(FEAT, 4) void fused_kernel(
    const float* __restrict__ emb,
    const int* __restrict__ starts,
    const int* __restrict__ ends,
    const int* __restrict__ num_nodes_p,
    float* __restrict__ colsum,
    float* __restrict__ supersum,
    float* __restrict__ out) {
    __shared__ int s_list[LIST_CAP];   // 16 KB
    __shared__ int s_cnt;
    const int c = blockIdx.x;
    const int tid = threadIdx.x;
    const int f = tid;
    const int num_nodes = *num_nodes_p;
    const int row_lo = c * CHUNK;
    const int row_hi = row_lo + CHUNK;
    const int4* starts4 = (const int4*)starts;
    const int4* ends4 = (const int4*)ends;

    if (tid == 0) s_cnt = 0;
    __syncthreads();
#pragma unroll
    for (int r = 0; r < MAX_NODES / (4 * FEAT); ++r) {   // 8 rounds x 1024 nodes
        const int vec = r * FEAT + tid;
        const int4 s4 = starts4[vec];
        const int4 e4 = ends4[vec];
        const int sv[4] = {s4.x, s4.y, s4.z, s4.w};
        const int ev[4] = {e4.x, e4.y, e4.z, e4.w};
        const int nb = vec * 4;
#pragma unroll
        for (int k = 0; k < 4; ++k) {
            const int node = nb + k;
            const int s = sv[k];
            const int e = ev[k];
            if (node < num_nodes && s <= e && s < T_TOKENS && e >= 0) {
                const int sc = s < 0 ? 0 : s;
                if (sc >= row_lo && sc < row_hi) {
                    int p = atomicAdd(&s_cnt, 1);
                    if (p < LIST_CAP) s_list[p] = (node << 4) | ((sc - row_lo) << 1);
                }
                const int e1 = e + 1;
                if (e1 < T_TOKENS && e1 >= row_lo && e1 < row_hi) {
                    int p = atomicAdd(&s_cnt, 1);
                    if (p < LIST_CAP) s_list[p] = (node << 4) | ((e1 - row_lo) << 1) | 1;
                }
            }
        }
    }
    __syncthreads();
    const int cnt = min(s_cnt, LIST_CAP);

    // gather signed emb rows ONCE, 8 loads in flight, fold into d0..d7
    float d0 = 0.f, d1 = 0.f, d2 = 0.f, d3 = 0.f;
    float d4 = 0.f, d5 = 0.f, d6 = 0.f, d7 = 0.f;
    {
        int j = 0;
        for (; j + 8 <= cnt; j += 8) {
            const int e0 = s_list[j + 0], e1 = s_list[j + 1];
            const int e2 = s_list[j + 2], e3 = s_list[j + 3];
            const int e4_ = s_list[j + 4], e5 = s_list[j + 5];
            const int e6 = s_list[j + 6], e7 = s_list[j + 7];
            const float v0 = emb[(size_t)(e0 >> 4) * FEAT + f];
            const float v1 = emb[(size_t)(e1 >> 4) * FEAT + f];
            const float v2 = emb[(size_t)(e2 >> 4) * FEAT + f];
            const float v3 = emb[(size_t)(e3 >> 4) * FEAT + f];
            const float v4 = emb[(size_t)(e4_ >> 4) * FEAT + f];
            const float v5 = emb[(size_t)(e5 >> 4) * FEAT + f];
            const float v6 = emb[(size_t)(e6 >> 4) * FEAT + f];
            const float v7 = emb[(size_t)(e7 >> 4) * FEAT + f];
            APPLY_EVENT(e0, v0);
            APPLY_EVENT(e1, v1);
            APPLY_EVENT(e2, v2);
            APPLY_EVENT(e3, v3);
            APPLY_EVENT(e4_, v4);
            APPLY_EVENT(e5, v5);
            APPLY_EVENT(e6, v6);
            APPLY_EVENT(e7, v7);
        }
        for (; j < cnt; ++j) {
            const int e0 = s_list[j];
            const float v0 = emb[(size_t)(e0 >> 4) * FEAT + f];
            APPLY_EVENT(e0, v0);
        }
    }
    // colsum = total chunk delta = sum of all signed event rows
    colsum[(size_t)c * FEAT + f] = ((d0 + d1) + (d2 + d3)) + ((d4 + d5) + (d6 + d7));

    cg::this_grid().sync();

    // phase 2a: blocks 0..31 build supersum (no atomics, no memset)
    if (c < NSUPER) {
        const float* cs = colsum + (size_t)c * SUPER * FEAT + f;
        float t0 = 0.f, t1 = 0.f, t2 = 0.f, t3 = 0.f;
        float t4 = 0.f, t5 = 0.f, t6 = 0.f, t7 = 0.f;
#pragma unroll
        for (int j = 0; j < SUPER; j += 8) {
            t0 += cs[(size_t)(j + 0) * FEAT];
            t1 += cs[(size_t)(j + 1) * FEAT];
            t2 += cs[(size_t)(j + 2) * FEAT];
            t3 += cs[(size_t)(j + 3) * FEAT];
            t4 += cs[(size_t)(j + 4) * FEAT];
            t5 += cs[(size_t)(j + 5) * FEAT];
            t6 += cs[(size_t)(j + 6) * FEAT];
            t7 += cs[(size_t)(j + 7) * FEAT];
        }
        supersum[(size_t)c * FEAT + f] = ((t0 + t1) + (t2 + t3)) + ((t4 + t5) + (t6 + t7));
    }

    cg::this_grid().sync();

    // phase 2b: 2-level exclusive prefix, 8 loads in flight
    const int sg = c >> 5;
    float r0 = 0.f, r1 = 0.f, r2 = 0.f, r3 = 0.f;
    float r4 = 0.f, r5 = 0.f, r6 = 0.f, r7 = 0.f;
    int i = 0;
    for (; i + 8 <= sg; i += 8) {
        r0 += supersum[(size_t)(i + 0) * FEAT + f];
        r1 += supersum[(size_t)(i + 1) * FEAT + f];
        r2 += supersum[(size_t)(i + 2) * FEAT + f];
        r3 += supersum[(size_t)(i + 3) * FEAT + f];
        r4 += supersum[(size_t)(i + 4) * FEAT + f];
        r5 += supersum[(size_t)(i + 5) * FEAT + f];
        r6 += supersum[(size_t)(i + 6) * FEAT + f];
        r7 += supersum[(size_t)(i + 7) * FEAT + f];
    }
    for (; i < sg; ++i) r0 += supersum[(size_t)i * FEAT + f];
    i = sg * SUPER;
    for (; i + 8 <= c; i += 8) {
        r0 += colsum[(size_t)(i + 0) * FEAT + f];
        r1 += colsum[(size_t)(i + 1) * FEAT + f];
        r2 += colsum[(size_t)(i + 2) * FEAT + f];
        r3 += colsum[(size_t)(i + 3) * FEAT + f];
        r4 += colsum[(size_t)(i + 4) * FEAT + f];
        r5 += colsum[(size_t)(i + 5) * FEAT + f];
        r6 += colsum[(size_t)(i + 6) * FEAT + f];
        r7 += colsum[(size_t)(i + 7) * FEAT + f];
    }
    for (; i < c; ++i) r0 += colsum[(size_t)i * FEAT + f];
    float run = ((r0 + r1) + (r2 + r3)) + ((r4 + r5) + (r6 + r7));

    float* o = out + (size_t)c * CHUNK * FEAT + f;
    run += d0; o[0 * FEAT] = run;
    run += d1; o[1 * FEAT] = run;
    run += d2; o[2 * FEAT] = run;
    run += d3; o[3 * FEAT] = run;
    run += d4; o[4 * FEAT] = run;
    run += d5; o[5 * FEAT] = run;
    run += d6; o[6 * FEAT] = run;
    run += d7; o[7 * FEAT] = run;
}

// ---------------------------------------------------------------------------
// Fallback path (previous verified 3-dispatch version) in case cooperative
// launch is unavailable / co-residency check fails.
// ---------------------------------------------------------------------------
__global__ __launch_bounds__(FEAT) void classify_colsum_kernel(
    const float* __restrict__ emb,
    const int* __restrict__ starts,
    const int* __restrict__ ends,
    const int* __restrict__ num_nodes_p,
    float* __restrict__ colsum,
    float* __restrict__ supersum,
    int* __restrict__ evcnt,
    int* __restrict__ evbuf) {
    __shared__ int s_list[LIST_CAP];
    __shared__ int s_cnt;
    const int c = blockIdx.x;
    const int tid = threadIdx.x;
    const int f = tid;
    const int num_nodes = *num_nodes_p;
    const int row_lo = c * CHUNK;
    const int row_hi = row_lo + CHUNK;
    const int4* starts4 = (const int4*)starts;
    const int4* ends4 = (const int4*)ends;

    if (tid == 0) s_cnt = 0;
    __syncthreads();
#pragma unroll
    for (int r = 0; r < MAX_NODES / (4 * FEAT); ++r) {
        const int vec = r * FEAT + tid;
        const int4 s4 = starts4[vec];
        const int4 e4 = ends4[vec];
        const int sv[4] = {s4.x, s4.y, s4.z, s4.w};
        const int ev[4] = {e4.x, e4.y, e4.z, e4.w};
        const int nb = vec * 4;
#pragma unroll
        for (int k = 0; k < 4; ++k) {
            const int node = nb + k;
            const int s = sv[k];
            const int e = ev[k];
            if (node < num_nodes && s <= e && s < T_TOKENS && e >= 0) {
                const int sc = s < 0 ? 0 : s;
                if (sc >= row_lo && sc < row_hi) {
                    int p = atomicAdd(&s_cnt, 1);
                    if (p < LIST_CAP) s_list[p] = (node << 4) | ((sc - row_lo) << 1);
                }
                const int e1 = e + 1;
                if (e1 < T_TOKENS && e1 >= row_lo && e1 < row_hi) {
                    int p = atomicAdd(&s_cnt, 1);
                    if (p < LIST_CAP) s_list[p] = (node << 4) | ((e1 - row_lo) << 1) | 1;
                }
            }
        }
    }
    __syncthreads();
    const int cnt = min(s_cnt, LIST_CAP);

    int* evb = evbuf + (size_t)c * EV_STRIDE;
    for (int j = tid; j < cnt; j += FEAT) evb[j] = s_list[j];
    if (tid == 0) evcnt[c] = cnt;

    float acc = 0.f;
    int j = 0;
    for (; j + 8 <= cnt; j += 8) {
        const int e0 = s_list[j + 0], e1 = s_list[j + 1];
        const int e2 = s_list[j + 2], e3 = s_list[j + 3];
        const int e4_ = s_list[j + 4], e5 = s_list[j + 5];
        const int e6 = s_list[j + 6], e7 = s_list[j + 7];
        const float v0 = emb[(size_t)(e0 >> 4) * FEAT + f];
        const float v1 = emb[(size_t)(e1 >> 4) * FEAT + f];
        const float v2 = emb[(size_t)(e2 >> 4) * FEAT + f];
        const float v3 = emb[(size_t)(e3 >> 4) * FEAT + f];
        const float v4 = emb[(size_t)(e4_ >> 4) * FEAT + f];
        const float v5 = emb[(size_t)(e5 >> 4) * FEAT + f];
        const float v6 = emb[(size_t)(e6 >> 4) * FEAT + f];
        const float v7 = emb[(size_t)(e7 >> 4) * FEAT + f];
        acc += (e0 & 1) ? -v0 : v0;
        acc += (e1 & 1) ? -v1 : v1;
        acc += (e2 & 1) ? -v2 : v2;
        acc += (e3 & 1) ? -v3 : v3;
        acc += (e4_ & 1) ? -v4 : v4;
        acc += (e5 & 1) ? -v5 : v5;
        acc += (e6 & 1) ? -v6 : v6;
        acc += (e7 & 1) ? -v7 : v7;
    }
    for (; j < cnt; ++j) {
        const int e0 = s_list[j];
        const float v0 = emb[(size_t)(e0 >> 4) * FEAT + f];
        acc += (e0 & 1) ? -v0 : v0;
    }
    colsum[(size_t)c * FEAT + f] = acc;
    atomicAdd(&supersum[(size_t)(c >> 5) * FEAT + f], acc);
}

__global__ __launch_bounds__(FEAT) void scan_kernel(
    const float* __restrict__ emb,
    const float* __restrict__ colsum,
    const float* __restrict__ supersum,
    const int* __restrict__ evcnt,
    const int* __restrict__ evbuf,
    float* __restrict__ out) {
    const int c = blockIdx.x;
    const int f = threadIdx.x;
    const int sg = c >> 5;

    const int cnt = evcnt[c];
    const int* evb = evbuf + (size_t)c * EV_STRIDE;

    float r0 = 0.f, r1 = 0.f, r2 = 0.f, r3 = 0.f;
    float r4 = 0.f, r5 = 0.f, r6 = 0.f, r7 = 0.f;
    int i = 0;
    for (; i + 8 <= sg; i += 8) {
        r0 += supersum[(size_t)(i + 0) * FEAT + f];
        r1 += supersum[(size_t)(i + 1) * FEAT + f];
        r2 += supersum[(size_t)(i + 2) * FEAT + f];
        r3 += supersum[(size_t)(i + 3) * FEAT + f];
        r4 += supersum[(size_t)(i + 4) * FEAT + f];
        r5 += supersum[(size_t)(i + 5) * FEAT + f];
        r6 += supersum[(size_t)(i + 6) * FEAT + f];
        r7 += supersum[(size_t)(i + 7) * FEAT + f];
    }
    for (; i < sg; ++i) r0 += supersum[(size_t)i * FEAT + f];
    i = sg * SUPER;
    for (; i + 8 <= c; i += 8) {
        r0 += colsum[(size_t)(i + 0) * FEAT + f];
        r1 += colsum[(size_t)(i + 1) * FEAT + f];
        r2 += colsum[(size_t)(i + 2) * FEAT + f];
        r3 += colsum[(size_t)(i + 3) * FEAT + f];
        r4 += colsum[(size_t)(i + 4) * FEAT + f];
        r5 += colsum[(size_t)(i + 5) * FEAT + f];
        r6 += colsum[(size_t)(i + 6) * FEAT + f];
        r7 += colsum[(size_t)(i + 7) * FEAT + f];
    }
    for (; i < c; ++i) r0 += colsum[(size_t)i * FEAT + f];
    float run = ((r0 + r1) + (r2 + r3)) + ((r4 + r5) + (r6 + r7));

    float d0 = 0.f, d1 = 0.f, d2 = 0.f, d3 = 0.f;
    float d4 = 0.f, d5 = 0.f, d6 = 0.f, d7 = 0.f;
    int j = 0;
    for (; j + 4 <= cnt; j += 4) {
        const int e0 = evb[j + 0], e1 = evb[j + 1];
        const int e2 = evb[j + 2], e3 = evb[j + 3];
        const float v0 = emb[(size_t)(e0 >> 4) * FEAT + f];
        const float v1 = emb[(size_t)(e1 >> 4) * FEAT + f];
        const float v2 = emb[(size_t)(e2 >> 4) * FEAT + f];
        const float v3 = emb[(size_t)(e3 >> 4) * FEAT + f];
        APPLY_EVENT(e0, v0);
        APPLY_EVENT(e1, v1);
        APPLY_EVENT(e2, v2);
        APPLY_EVENT(e3, v3);
    }
    for (; j < cnt; ++j) {
        const int e0 = evb[j];
        const float v0 = emb[(size_t)(e0 >> 4) * FEAT + f];
        APPLY_EVENT(e0, v0);
    }

    float* o = out + (size_t)c * CHUNK * FEAT + f;
    run += d0; o[0 * FEAT] = run;
    run += d1; o[1 * FEAT] = run;
    run += d2; o[2 * FEAT] = run;
    run += d3; o[3 * FEAT] = run;
    run += d4; o[4 * FEAT] = run;
    run += d5; o[5 * FEAT] = run;
    run += d6; o[6 * FEAT] = run;
    run += d7; o[7 * FEAT] = run;
}

extern "C" void kernel_launch(void* const* d_in, const int* in_sizes, int n_in,
                              void* d_out, int out_size, void* d_ws, size_t ws_size,
                              hipStream_t stream) {
    (void)in_sizes; (void)n_in; (void)out_size; (void)ws_size;
    const float* emb     = (const float*)d_in[0];
    const int* starts    = (const int*)d_in[1];
    const int* ends      = (const int*)d_in[2];
    const int* num_nodes = (const int*)d_in[3];
    float* out           = (float*)d_out;

    float* colsum   = (float*)d_ws;                              // 1 MB
    float* supersum = colsum + (size_t)NCHUNKS * FEAT;           // 32 KB
    int* evcnt      = (int*)(supersum + (size_t)NSUPER * FEAT);  // 4 KB (fallback)
    int* evbuf      = evcnt + NCHUNKS;                           // 16 MB (fallback)

    // One-time co-residency check for the cooperative path:
    // 1024 blocks need 4 blocks/CU on 256 CUs.
    static int s_coop = -1;
    if (s_coop < 0) {
        int nb = 0;
        hipError_t oe = hipOccupancyMaxActiveBlocksPerMultiprocessor(&nb, fused_kernel, FEAT, 0);
        s_coop = (oe == hipSuccess && nb > 0 && nb * 256 >= NCHUNKS) ? 1 : 0;
    }

    if (s_coop == 1) {
        void* args[] = {(void*)&emb, (void*)&starts, (void*)&ends, (void*)&num_nodes,
                        (void*)&colsum, (void*)&supersum, (void*)&out};
        hipError_t le = hipLaunchCooperativeKernel(fused_kernel, dim3(NCHUNKS), dim3(FEAT),
                                                   args, 0, stream);
        if (le == hipSuccess) return;
        s_coop = 0;  // fall through to safe path
    }

    // Fallback: previous verified 3-dispatch pipeline.
    hipMemsetAsync(supersum, 0, (size_t)NSUPER * FEAT * sizeof(float), stream);
    classify_colsum_kernel<<<NCHUNKS, FEAT, 0, stream>>>(
        emb, starts, ends, num_nodes, colsum, supersum, evcnt, evbuf);
    scan_kernel<<<NCHUNKS, FEAT, 0, stream>>>(
        emb, colsum, supersum, evcnt, evbuf, out);
}

// Round 2
// 104.553 us; speedup vs baseline: 3.0143x; 3.0143x over previous
//
#include <hip/hip_runtime.h>

#define T_TOKENS 8192
#define MAX_NODES 8192
#define FEAT 256
#define NCHUNKS 1024
#define CHUNK 8                  // T_TOKENS / NCHUNKS
#define NSUPER 32
#define SUPER 32                 // chunks per supergroup
#define LIST_CAP 4096            // events/chunk cap (expected ~18, huge margin)
#define EV_STRIDE LIST_CAP
#define FLAG_PAD 64              // ints of padding after cflag+sflag

// entry = (node << 4) | (local_row << 1) | sign, local_row in [0,8)
#define APPLY_EVENT(eV, vV)                          \
    {                                                \
        const float sv_ = ((eV) & 1) ? -(vV) : (vV); \
        const int lr_ = ((eV) >> 1) & 7;             \
        d0 += (lr_ == 0) ? sv_ : 0.f;                \
        d1 += (lr_ == 1) ? sv_ : 0.f;                \
        d2 += (lr_ == 2) ? sv_ : 0.f;                \
        d3 += (lr_ == 3) ? sv_ : 0.f;                \
        d4 += (lr_ == 4) ? sv_ : 0.f;                \
        d5 += (lr_ == 5) ? sv_ : 0.f;                \
        d6 += (lr_ == 6) ? sv_ : 0.f;                \
        d7 += (lr_ == 7) ? sv_ : 0.f;                \
    }

// Device-coherent (cross-XCD safe) float load / store helpers.
__device__ __forceinline__ float agld(const float* p) {
    return __hip_atomic_load((const float*)p, __ATOMIC_RELAXED, __HIP_MEMORY_SCOPE_AGENT);
}
__device__ __forceinline__ void agst(float* p, float v) {
    __hip_atomic_store(p, v, __ATOMIC_RELAXED, __HIP_MEMORY_SCOPE_AGENT);
}

// Pipelined (8 in flight) column-f sum over n rows of a [n][FEAT] array,
// using agent-scope loads (data written by other blocks this kernel).
__device__ __forceinline__ float sum_rows(const float* p, int n, int f) {
    float r0 = 0.f, r1 = 0.f, r2 = 0.f, r3 = 0.f;
    float r4 = 0.f, r5 = 0.f, r6 = 0.f, r7 = 0.f;
    int i = 0;
    for (; i + 8 <= n; i += 8) {
        r0 += agld(p + (size_t)(i + 0) * FEAT + f);
        r1 += agld(p + (size_t)(i + 1) * FEAT + f);
        r2 += agld(p + (size_t)(i + 2) * FEAT + f);
        r3 += agld(p + (size_t)(i + 3) * FEAT + f);
        r4 += agld(p + (size_t)(i + 4) * FEAT + f);
        r5 += agld(p + (size_t)(i + 5) * FEAT + f);
        r6 += agld(p + (size_t)(i + 6) * FEAT + f);
        r7 += agld(p + (size_t)(i + 7) * FEAT + f);
    }
    for (; i < n; ++i) r0 += agld(p + (size_t)i * FEAT + f);
    return ((r0 + r1) + (r2 + r3)) + ((r4 + r5) + (r6 + r7));
}

__device__ __forceinline__ void spin_flag(const int* p) {
    while (__hip_atomic_load((const int*)p, __ATOMIC_RELAXED, __HIP_MEMORY_SCOPE_AGENT) == 0)
        __builtin_amdgcn_s_sleep(1);
}

// ---------------------------------------------------------------------------
// Single fused kernel, decoupled-flag version (no grid barrier):
// Phase 1 : block c classifies nodes (only rounds < num_nodes), gathers the
//           ~18 signed emb rows ONCE into registers d0..d7; colsum = sum(d).
//           Publishes colsum row with a per-chunk flag (agent release).
// Publish : block with (c&31)==31 polls its group's 31 predecessor flags,
//           sums their colsum rows (+own, in-register), publishes supersum[sg]
//           with a per-supergroup flag. Its own exclusive in-group prefix is
//           a free byproduct.
// Prefix  : block c polls <=31 sflags + <=30 cflags (one lane per flag, all
//           distinct cachelines, s_sleep throttled), then 2-level exclusive
//           prefix with 8 loads in flight, then out rows = run + cumsum(d).
// Dependencies are strictly backward (block c only waits on blocks < c) and
// all 1024 blocks are co-resident (4/CU, gated host-side) -> no deadlock.
// ---------------------------------------------------------------------------
__global__ __launch_bounds__(FEAT, 4) void fused_flag_kernel(
    const float* __restrict__ emb,
    const int* __restrict__ starts,
    const int* __restrict__ ends,
    const int* __restrict__ num_nodes_p,
    float* __restrict__ colsum,
    float* __restrict__ supersum,
    int* __restrict__ cflag,
    int* __restrict__ sflag,
    float* __restrict__ out) {
    __shared__ int s_list[LIST_CAP];   // 16 KB
    __shared__ int s_cnt;
    const int c = blockIdx.x;
    const int tid = threadIdx.x;
    const int f = tid;
    const int num_nodes = *num_nodes_p;
    const int row_lo = c * CHUNK;
    const int row_hi = row_lo + CHUNK;
    const int4* starts4 = (const int4*)starts;
    const int4* ends4 = (const int4*)ends;

    if (tid == 0) s_cnt = 0;
    __syncthreads();
    // only scan rounds that can contain valid nodes (1024 nodes/round)
    const int R = min(MAX_NODES / (4 * FEAT), (num_nodes + 1023) >> 10);
    for (int r = 0; r < R; ++r) {
        const int vec = r * FEAT + tid;
        const int4 s4 = starts4[vec];
        const int4 e4 = ends4[vec];
        const int sv[4] = {s4.x, s4.y, s4.z, s4.w};
        const int ev[4] = {e4.x, e4.y, e4.z, e4.w};
        const int nb = vec * 4;
#pragma unroll
        for (int k = 0; k < 4; ++k) {
            const int node = nb + k;
            const int s = sv[k];
            const int e = ev[k];
            if (node < num_nodes && s <= e && s < T_TOKENS && e >= 0) {
                const int sc = s < 0 ? 0 : s;
                if (sc >= row_lo && sc < row_hi) {
                    int p = atomicAdd(&s_cnt, 1);
                    if (p < LIST_CAP) s_list[p] = (node << 4) | ((sc - row_lo) << 1);
                }
                const int e1 = e + 1;
                if (e1 < T_TOKENS && e1 >= row_lo && e1 < row_hi) {
                    int p = atomicAdd(&s_cnt, 1);
                    if (p < LIST_CAP) s_list[p] = (node << 4) | ((e1 - row_lo) << 1) | 1;
                }
            }
        }
    }
    __syncthreads();
    const int cnt = min(s_cnt, LIST_CAP);

    // gather signed emb rows ONCE, 8 loads in flight, fold into d0..d7
    float d0 = 0.f, d1 = 0.f, d2 = 0.f, d3 = 0.f;
    float d4 = 0.f, d5 = 0.f, d6 = 0.f, d7 = 0.f;
    {
        int j = 0;
        for (; j + 8 <= cnt; j += 8) {
            const int e0 = s_list[j + 0], e1 = s_list[j + 1];
            const int e2 = s_list[j + 2], e3 = s_list[j + 3];
            const int e4_ = s_list[j + 4], e5 = s_list[j + 5];
            const int e6 = s_list[j + 6], e7 = s_list[j + 7];
            const float v0 = emb[(size_t)(e0 >> 4) * FEAT + f];
            const float v1 = emb[(size_t)(e1 >> 4) * FEAT + f];
            const float v2 = emb[(size_t)(e2 >> 4) * FEAT + f];
            const float v3 = emb[(size_t)(e3 >> 4) * FEAT + f];
            const float v4 = emb[(size_t)(e4_ >> 4) * FEAT + f];
            const float v5 = emb[(size_t)(e5 >> 4) * FEAT + f];
            const float v6 = emb[(size_t)(e6 >> 4) * FEAT + f];
            const float v7 = emb[(size_t)(e7 >> 4) * FEAT + f];
            APPLY_EVENT(e0, v0);
            APPLY_EVENT(e1, v1);
            APPLY_EVENT(e2, v2);
            APPLY_EVENT(e3, v3);
            APPLY_EVENT(e4_, v4);
            APPLY_EVENT(e5, v5);
            APPLY_EVENT(e6, v6);
            APPLY_EVENT(e7, v7);
        }
        for (; j < cnt; ++j) {
            const int e0 = s_list[j];
            const float v0 = emb[(size_t)(e0 >> 4) * FEAT + f];
            APPLY_EVENT(e0, v0);
        }
    }
    const float csum = ((d0 + d1) + (d2 + d3)) + ((d4 + d5) + (d6 + d7));

    // publish own colsum row (device-coherent), then release the chunk flag
    agst(&colsum[(size_t)c * FEAT + f], csum);
    __syncthreads();   // drains all lanes' stores (vmcnt 0) before flag
    if (tid == 0)
        __hip_atomic_store(&cflag[c], 1, __ATOMIC_RELEASE, __HIP_MEMORY_SCOPE_AGENT);

    const int sg = c >> 5;
    const int lc = c & 31;
    const int base = sg * SUPER;

    float run;
    if (lc == SUPER - 1) {
        // ---- supergroup publisher ----
        if (tid < SUPER - 1) spin_flag(&cflag[base + tid]);
        __syncthreads();
        const float grp_excl = sum_rows(colsum + (size_t)base * FEAT, SUPER - 1, f);
        agst(&supersum[(size_t)sg * FEAT + f], grp_excl + csum);
        __syncthreads();
        if (tid == 0)
            __hip_atomic_store(&sflag[sg], 1, __ATOMIC_RELEASE, __HIP_MEMORY_SCOPE_AGENT);
        // own prefix: supergroup prefixes + in-group exclusive (already summed)
        if (tid < sg) spin_flag(&sflag[tid]);
        __syncthreads();
        run = sum_rows(supersum, sg, f) + grp_excl;
    } else {
        // one lane per needed flag; all distinct cachelines
        if (tid < sg) spin_flag(&sflag[tid]);
        else if (tid >= 32 && tid < 32 + lc) spin_flag(&cflag[base + (tid - 32)]);
        __syncthreads();
        run = sum_rows(supersum, sg, f) + sum_rows(colsum + (size_t)base * FEAT, lc, f);
    }

    float* o = out + (size_t)c * CHUNK * FEAT + f;
    run += d0; o[0 * FEAT] = run;
    run += d1; o[1 * FEAT] = run;
    run += d2; o[2 * FEAT] = run;
    run += d3; o[3 * FEAT] = run;
    run += d4; o[4 * FEAT] = run;
    run += d5; o[5 * FEAT] = run;
    run += d6; o[6 * FEAT] = run;
    run += d7; o[7 * FEAT] = run;
}

// ---------------------------------------------------------------------------
// Fallback path (verified 84 µs 3-dispatch version) if co-residency fails.
// ---------------------------------------------------------------------------
__global__ __launch_bounds__(FEAT) void classify_colsum_kernel(
    const float* __restrict__ emb,
    const int* __restrict__ starts,
    const int* __restrict__ ends,
    const int* __restrict__ num_nodes_p,
    float* __restrict__ colsum,
    float* __restrict__ supersum,
    int* __restrict__ evcnt,
    int* __restrict__ evbuf) {
    __shared__ int s_list[LIST_CAP];
    __shared__ int s_cnt;
    const int c = blockIdx.x;
    const int tid = threadIdx.x;
    const int f = tid;
    const int num_nodes = *num_nodes_p;
    const int row_lo = c * CHUNK;
    const int row_hi = row_lo + CHUNK;
    const int4* starts4 = (const int4*)starts;
    const int4* ends4 = (const int4*)ends;

    if (tid == 0) s_cnt = 0;
    __syncthreads();
#pragma unroll
    for (int r = 0; r < MAX_NODES / (4 * FEAT); ++r) {
        const int vec = r * FEAT + tid;
        const int4 s4 = starts4[vec];
        const int4 e4 = ends4[vec];
        const int sv[4] = {s4.x, s4.y, s4.z, s4.w};
        const int ev[4] = {e4.x, e4.y, e4.z, e4.w};
        const int nb = vec * 4;
#pragma unroll
        for (int k = 0; k < 4; ++k) {
            const int node = nb + k;
            const int s = sv[k];
            const int e = ev[k];
            if (node < num_nodes && s <= e && s < T_TOKENS && e >= 0) {
                const int sc = s < 0 ? 0 : s;
                if (sc >= row_lo && sc < row_hi) {
                    int p = atomicAdd(&s_cnt, 1);
                    if (p < LIST_CAP) s_list[p] = (node << 4) | ((sc - row_lo) << 1);
                }
                const int e1 = e + 1;
                if (e1 < T_TOKENS && e1 >= row_lo && e1 < row_hi) {
                    int p = atomicAdd(&s_cnt, 1);
                    if (p < LIST_CAP) s_list[p] = (node << 4) | ((e1 - row_lo) << 1) | 1;
                }
            }
        }
    }
    __syncthreads();
    const int cnt = min(s_cnt, LIST_CAP);

    int* evb = evbuf + (size_t)c * EV_STRIDE;
    for (int j = tid; j < cnt; j += FEAT) evb[j] = s_list[j];
    if (tid == 0) evcnt[c] = cnt;

    float acc = 0.f;
    int j = 0;
    for (; j + 8 <= cnt; j += 8) {
        const int e0 = s_list[j + 0], e1 = s_list[j + 1];
        const int e2 = s_list[j + 2], e3 = s_list[j + 3];
        const int e4_ = s_list[j + 4], e5 = s_list[j + 5];
        const int e6 = s_list[j + 6], e7 = s_list[j + 7];
        const float v0 = emb[(size_t)(e0 >> 4) * FEAT + f];
        const float v1 = emb[(size_t)(e1 >> 4) * FEAT + f];
        const float v2 = emb[(size_t)(e2 >> 4) * FEAT + f];
        const float v3 = emb[(size_t)(e3 >> 4) * FEAT + f];
        const float v4 = emb[(size_t)(e4_ >> 4) * FEAT + f];
        const float v5 = emb[(size_t)(e5 >> 4) * FEAT + f];
        const float v6 = emb[(size_t)(e6 >> 4) * FEAT + f];
        const float v7 = emb[(size_t)(e7 >> 4) * FEAT + f];
        acc += (e0 & 1) ? -v0 : v0;
        acc += (e1 & 1) ? -v1 : v1;
        acc += (e2 & 1) ? -v2 : v2;
        acc += (e3 & 1) ? -v3 : v3;
        acc += (e4_ & 1) ? -v4 : v4;
        acc += (e5 & 1) ? -v5 : v5;
        acc += (e6 & 1) ? -v6 : v6;
        acc += (e7 & 1) ? -v7 : v7;
    }
    for (; j < cnt; ++j) {
        const int e0 = s_list[j];
        const float v0 = emb[(size_t)(e0 >> 4) * FEAT + f];
        acc += (e0 & 1) ? -v0 : v0;
    }
    colsum[(size_t)c * FEAT + f] = acc;
    atomicAdd(&supersum[(size_t)(c >> 5) * FEAT + f], acc);
}

__global__ __launch_bounds__(FEAT) void scan_kernel(
    const float* __restrict__ emb,
    const float* __restrict__ colsum,
    const float* __restrict__ supersum,
    const int* __restrict__ evcnt,
    const int* __restrict__ evbuf,
    float* __restrict__ out) {
    const int c = blockIdx.x;
    const int f = threadIdx.x;
    const int sg = c >> 5;

    const int cnt = evcnt[c];
    const int* evb = evbuf + (size_t)c * EV_STRIDE;

    float r0 = 0.f, r1 = 0.f, r2 = 0.f, r3 = 0.f;
    float r4 = 0.f, r5 = 0.f, r6 = 0.f, r7 = 0.f;
    int i = 0;
    for (; i + 8 <= sg; i += 8) {
        r0 += supersum[(size_t)(i + 0) * FEAT + f];
        r1 += supersum[(size_t)(i + 1) * FEAT + f];
        r2 += supersum[(size_t)(i + 2) * FEAT + f];
        r3 += supersum[(size_t)(i + 3) * FEAT + f];
        r4 += supersum[(size_t)(i + 4) * FEAT + f];
        r5 += supersum[(size_t)(i + 5) * FEAT + f];
        r6 += supersum[(size_t)(i + 6) * FEAT + f];
        r7 += supersum[(size_t)(i + 7) * FEAT + f];
    }
    for (; i < sg; ++i) r0 += supersum[(size_t)i * FEAT + f];
    i = sg * SUPER;
    for (; i + 8 <= c; i += 8) {
        r0 += colsum[(size_t)(i + 0) * FEAT + f];
        r1 += colsum[(size_t)(i + 1) * FEAT + f];
        r2 += colsum[(size_t)(i + 2) * FEAT + f];
        r3 += colsum[(size_t)(i + 3) * FEAT + f];
        r4 += colsum[(size_t)(i + 4) * FEAT + f];
        r5 += colsum[(size_t)(i + 5) * FEAT + f];
        r6 += colsum[(size_t)(i + 6) * FEAT + f];
        r7 += colsum[(size_t)(i + 7) * FEAT + f];
    }
    for (; i < c; ++i) r0 += colsum[(size_t)i * FEAT + f];
    float run = ((r0 + r1) + (r2 + r3)) + ((r4 + r5) + (r6 + r7));

    float d0 = 0.f, d1 = 0.f, d2 = 0.f, d3 = 0.f;
    float d4 = 0.f, d5 = 0.f, d6 = 0.f, d7 = 0.f;
    int j = 0;
    for (; j + 4 <= cnt; j += 4) {
        const int e0 = evb[j + 0], e1 = evb[j + 1];
        const int e2 = evb[j + 2], e3 = evb[j + 3];
        const float v0 = emb[(size_t)(e0 >> 4) * FEAT + f];
        const float v1 = emb[(size_t)(e1 >> 4) * FEAT + f];
        const float v2 = emb[(size_t)(e2 >> 4) * FEAT + f];
        const float v3 = emb[(size_t)(e3 >> 4) * FEAT + f];
        APPLY_EVENT(e0, v0);
        APPLY_EVENT(e1, v1);
        APPLY_EVENT(e2, v2);
        APPLY_EVENT(e3, v3);
    }
    for (; j < cnt; ++j) {
        const int e0 = evb[j];
        const float v0 = emb[(size_t)(e0 >> 4) * FEAT + f];
        APPLY_EVENT(e0, v0);
    }

    float* o = out + (size_t)c * CHUNK * FEAT + f;
    run += d0; o[0 * FEAT] = run;
    run += d1; o[1 * FEAT] = run;
    run += d2; o[2 * FEAT] = run;
    run += d3; o[3 * FEAT] = run;
    run += d4; o[4 * FEAT] = run;
    run += d5; o[5 * FEAT] = run;
    run += d6; o[6 * FEAT] = run;
    run += d7; o[7 * FEAT] = run;
}

extern "C" void kernel_launch(void* const* d_in, const int* in_sizes, int n_in,
                              void* d_out, int out_size, void* d_ws, size_t ws_size,
                              hipStream_t stream) {
    (void)in_sizes; (void)n_in; (void)out_size; (void)ws_size;
    const float* emb     = (const float*)d_in[0];
    const int* starts    = (const int*)d_in[1];
    const int* ends      = (const int*)d_in[2];
    const int* num_nodes = (const int*)d_in[3];
    float* out           = (float*)d_out;

    // workspace layout: [cflag 1024][sflag 32][pad][colsum 1MB][supersum 32KB][evcnt][evbuf]
    int* cflag      = (int*)d_ws;
    int* sflag      = cflag + NCHUNKS;
    float* colsum   = (float*)(cflag + NCHUNKS + NSUPER + FLAG_PAD);
    float* supersum = colsum + (size_t)NCHUNKS * FEAT;
    int* evcnt      = (int*)(supersum + (size_t)NSUPER * FEAT);   // fallback only
    int* evbuf      = evcnt + NCHUNKS;                            // fallback only

    // Deadlock gate: flag design requires all 1024 blocks co-resident (4/CU).
    static int s_flags_ok = -1;
    if (s_flags_ok < 0) {
        int nb = 0;
        hipError_t oe = hipOccupancyMaxActiveBlocksPerMultiprocessor(&nb, fused_flag_kernel, FEAT, 0);
        s_flags_ok = (oe == hipSuccess && nb >= 4) ? 1 : 0;
    }

    if (s_flags_ok == 1) {
        // zero the chunk + supergroup flags (4.4 KB), then one fused kernel
        hipMemsetAsync(cflag, 0, (size_t)(NCHUNKS + NSUPER + FLAG_PAD) * sizeof(int), stream);
        fused_flag_kernel<<<NCHUNKS, FEAT, 0, stream>>>(
            emb, starts, ends, num_nodes, colsum, supersum, cflag, sflag, out);
        return;
    }

    // Fallback: verified 3-dispatch pipeline.
    hipMemsetAsync(supersum, 0, (size_t)NSUPER * FEAT * sizeof(float), stream);
    classify_colsum_kernel<<<NCHUNKS, FEAT, 0, stream>>>(
        emb, starts, ends, num_nodes, colsum, supersum, evcnt, evbuf);
    scan_kernel<<<NCHUNKS, FEAT, 0, stream>>>(
        emb, colsum, supersum, evcnt, evbuf, out);
}